// Round 1
// baseline (234.783 us; speedup 1.0000x reference)
//
#include <hip/hip_runtime.h>
#include <hip/hip_bf16.h>

// Weighted BP decoder, (3,6)-regular Tanner graph.
// Layout exploited: edges are row-major nonzeros of H, so check r owns edges
// 6r..6r+5 (consecutive) -> check-side extrinsic products are in-register
// prefix/suffix products (c_prod_idx input is unused).
// Messages stored in log2 domain: d = c2v/ln2, so
//   exp(sum w*c2v + llr*lw) = exp2(sum w*d + llr*lw*log2e)   (weights unscaled!)
//   d_new = log2(1+kappa*p) - log2(1-kappa*p)
// One LDS array, updated in place; 2 barriers/iter.

namespace {

constexpr int T      = 512;   // threads/block == checks
constexpr int ROWS   = 2;     // batch rows per block (float2-packed)
constexpr int MCHK   = 512;
constexpr int NVAR   = 1024;
constexpr int EEDG   = 3072;
constexpr int NITER  = 10;
constexpr int STRIDE = 7;     // float2 slots per check (6 + 1 pad, odd -> bank spread)
constexpr int BATCH  = 8192;
constexpr int NOUT   = 512;   // N - M outputs per row

constexpr float LOG2E = 1.4426950408889634f;
constexpr float LN2   = 0.6931471805599453f;
constexpr float KAPPA = 0.999995f;

__device__ __forceinline__ float fast_exp2(float x) { return __builtin_amdgcn_exp2f(x); }
__device__ __forceinline__ float fast_log2(float x) { return __builtin_amdgcn_logf(x); }
__device__ __forceinline__ float fast_rcp (float x) { return __builtin_amdgcn_rcpf(x); }

__global__ __launch_bounds__(T, 4)
void bp_decode(const float* __restrict__ llr,
               const float* __restrict__ w_iter,
               const float* __restrict__ llr_iter,
               const float* __restrict__ w_final,
               const float* __restrict__ llr_final,
               const int*  __restrict__ v_sum_idx,
               const int*  __restrict__ edge_var,
               const int*  __restrict__ final_idx,
               float* __restrict__ out)
{
    __shared__ float2 Ad[MCHK * STRIDE];   // 28672 B, d-messages (log2 domain), 2 rows packed

    const int  tid = threadIdx.x;
    const long b0  = (long)blockIdx.x * ROWS;

    // ---- init: c2v = 0 -> d = 0 ----
    #pragma unroll
    for (int k = 0; k < STRIDE; ++k)
        Ad[k * T + tid] = make_float2(0.f, 0.f);

    // ---- static per-thread graph data (my check = tid, my edges = 6*tid..6*tid+5) ----
    int nb[12];   // variable-side extrinsic neighbor edges of my 6 edges
    {
        const int4* p = (const int4*)(v_sum_idx + 12 * tid);  // 48B-aligned
        int4 q0 = p[0], q1 = p[1], q2 = p[2];
        nb[0]=q0.x; nb[1]=q0.y; nb[2]=q0.z; nb[3]=q0.w;
        nb[4]=q1.x; nb[5]=q1.y; nb[6]=q1.z; nb[7]=q1.w;
        nb[8]=q2.x; nb[9]=q2.y; nb[10]=q2.z; nb[11]=q2.w;
    }
    int goff[12];                     // padded LDS slot of each neighbor edge
    #pragma unroll
    for (int j = 0; j < 12; ++j)
        goff[j] = (nb[j] / 6) * STRIDE + (nb[j] % 6);

    int var[6];
    {
        const int2* p = (const int2*)(edge_var + 6 * tid);    // 24B-aligned
        int2 q0 = p[0], q1 = p[1], q2 = p[2];
        var[0]=q0.x; var[1]=q0.y; var[2]=q1.x; var[3]=q1.y; var[4]=q2.x; var[5]=q2.y;
    }

    // channel LLRs for my 6 variables, both batch rows (stride-2-ish gather, once)
    float Lx[6], Ly[6];
    #pragma unroll
    for (int j = 0; j < 6; ++j) {
        Lx[j] = llr[ b0      * NVAR + var[j]];
        Ly[j] = llr[(b0 + 1) * NVAR + var[j]];
    }

    __syncthreads();

    const int own = STRIDE * tid;

    #pragma unroll 1
    for (int it = 0; it < NITER; ++it) {
        // per-iteration weights: my 6 edges x 2 = 12 consecutive floats (coalesced)
        const float* wit = w_iter + it * (EEDG * 2) + 12 * tid;
        float4 wa = ((const float4*)wit)[0];
        float4 wb = ((const float4*)wit)[1];
        float4 wc = ((const float4*)wit)[2];
        float w[12] = {wa.x,wa.y,wa.z,wa.w, wb.x,wb.y,wb.z,wb.w, wc.x,wc.y,wc.z,wc.w};

        // per-iteration llr multipliers (4KB L1-hot table, near-stride-2 access)
        const float* lit = llr_iter + it * NVAR;
        float li[6];
        #pragma unroll
        for (int j = 0; j < 6; ++j) li[j] = lit[var[j]] * LOG2E;

        // gather extrinsic d-messages (12 x ds_read_b64)
        float2 g[12];
        #pragma unroll
        for (int j = 0; j < 12; ++j) g[j] = Ad[goff[j]];

        __syncthreads();   // all gathers landed before anyone overwrites in place

        // v2c: t = tanh(0.5*(sum w*c2v + llr*lw)) = 1 - 2/(exp2(arg)+1)
        float tx[6], ty[6];
        #pragma unroll
        for (int j = 0; j < 6; ++j) {
            float ax = fmaf(w[2*j], g[2*j].x, fmaf(w[2*j+1], g[2*j+1].x, Lx[j]*li[j]));
            float ay = fmaf(w[2*j], g[2*j].y, fmaf(w[2*j+1], g[2*j+1].y, Ly[j]*li[j]));
            float zx = fast_exp2(ax);
            float zy = fast_exp2(ay);
            tx[j] = fmaf(-2.f, fast_rcp(zx + 1.f), 1.f);   // saturates to +/-1, no NaN
            ty[j] = fmaf(-2.f, fast_rcp(zy + 1.f), 1.f);
        }

        // check-side all-but-one products, in registers (edges of a check are mine)
        float px[6], py[6];
        {
            float P1=tx[0], P2=P1*tx[1], P3=P2*tx[2], P4=P3*tx[3], P5=P4*tx[4];
            float S4=tx[5], S3=S4*tx[4], S2=S3*tx[3], S1=S2*tx[2], S0=S1*tx[1];
            px[0]=S0; px[1]=P1*S1; px[2]=P2*S2; px[3]=P3*S3; px[4]=P4*S4; px[5]=P5;
        }
        {
            float P1=ty[0], P2=P1*ty[1], P3=P2*ty[2], P4=P3*ty[3], P5=P4*ty[4];
            float S4=ty[5], S3=S4*ty[4], S2=S3*ty[3], S1=S2*ty[2], S0=S1*ty[1];
            py[0]=S0; py[1]=P1*S1; py[2]=P2*S2; py[3]=P3*S3; py[4]=P4*S4; py[5]=P5;
        }

        // c2v in log2 domain, written in place to my own 6 slots
        #pragma unroll
        for (int j = 0; j < 6; ++j) {
            float xx = KAPPA * px[j];
            float xy = KAPPA * py[j];
            float dx = fast_log2(1.f + xx) - fast_log2(1.f - xx);
            float dy = fast_log2(1.f + xy) - fast_log2(1.f - xy);
            Ad[own + j] = make_float2(dx, dy);
        }

        __syncthreads();   // writes visible before next iteration's gathers
    }

    // ---- final marginalization: variable n = tid (exactly the 512 output vars) ----
    int f0 = final_idx[3*tid], f1 = final_idx[3*tid + 1], f2 = final_idx[3*tid + 2];
    float2 d0 = Ad[(f0 / 6) * STRIDE + (f0 % 6)];
    float2 d1 = Ad[(f1 / 6) * STRIDE + (f1 % 6)];
    float2 d2 = Ad[(f2 / 6) * STRIDE + (f2 % 6)];
    float wf0 = w_final[3*tid], wf1 = w_final[3*tid + 1], wf2 = w_final[3*tid + 2];
    float lf  = llr_final[tid];
    float l0  = llr[ b0      * NVAR + tid];
    float l1  = llr[(b0 + 1) * NVAR + tid];

    float finx = (d0.x*wf0 + d1.x*wf1 + d2.x*wf2) * LN2;   // c2v = ln2 * d
    float finy = (d0.y*wf0 + d1.y*wf1 + d2.y*wf2) * LN2;
    float vx = fmaf(l0, lf, finx);
    float vy = fmaf(l1, lf, finy);
    float ox = fast_rcp(1.f + fast_exp2(-vx * LOG2E));     // sigmoid
    float oy = fast_rcp(1.f + fast_exp2(-vy * LOG2E));

    out[ b0      * NOUT + tid] = ox;
    out[(b0 + 1) * NOUT + tid] = oy;
}

} // namespace

extern "C" void kernel_launch(void* const* d_in, const int* in_sizes, int n_in,
                              void* d_out, int out_size, void* d_ws, size_t ws_size,
                              hipStream_t stream)
{
    const float* llr       = (const float*)d_in[0];
    const float* w_iter    = (const float*)d_in[1];
    const float* llr_iter  = (const float*)d_in[2];
    const float* w_final   = (const float*)d_in[3];
    const float* llr_final = (const float*)d_in[4];
    const int*   v_sum_idx = (const int*)d_in[5];
    // d_in[6] = c_prod_idx: unused (check groups are consecutive by construction)
    const int*   edge_var  = (const int*)d_in[7];
    const int*   final_idx = (const int*)d_in[8];
    float* outp = (float*)d_out;

    dim3 grid(BATCH / ROWS), block(T);
    hipLaunchKernelGGL(bp_decode, grid, block, 0, stream,
                       llr, w_iter, llr_iter, w_final, llr_final,
                       v_sum_idx, edge_var, final_idx, outp);
}

// Round 2
// 218.985 us; speedup vs baseline: 1.0721x; 1.0721x over previous
//
#include <hip/hip_runtime.h>
#include <hip/hip_bf16.h>

// Weighted BP decoder, (3,6)-regular Tanner graph.
// Check r owns edges 6r..6r+5 (row-major nonzeros of H) -> check-side extrinsic
// products are in-register prefix/suffix products (c_prod_idx unused).
//
// Messages in log2 domain: d = c2v/ln2. With z = exp2(a), t = tanh(a*ln2/2)
// = (z-1)/(z+1); extrinsic product p = A/B with A = prod(z-1), B = prod(z+1)
// (all-but-one). Then
//   d_new = log2((1+kappa*p)/(1-kappa*p)) = log2(B + kappa*A) - log2(B - kappa*A)
// -> per edge-row transcendentals: exp2 + 2*log2 (no rcp; tanh never formed).
// z clamped to <= 2^24 so 5-way products stay finite (<= 2^120) and B >= |A|
// guarantees both log args >= (1-kappa)*B > 0.
//
// Both batch rows are computed on ext_vector_type(2) float so the backend can
// emit packed v_pk_fma_f32 / v_pk_mul_f32 (2x f32 per issue slot).

namespace {

typedef float v2f __attribute__((ext_vector_type(2)));

constexpr int T      = 512;   // threads/block == checks
constexpr int ROWS   = 2;     // batch rows per block (float2-packed)
constexpr int MCHK   = 512;
constexpr int NVAR   = 1024;
constexpr int EEDG   = 3072;
constexpr int NITER  = 10;
constexpr int STRIDE = 7;     // v2f slots per check (6 + 1 pad, odd -> bank spread)
constexpr int BATCH  = 8192;
constexpr int NOUT   = 512;   // N - M outputs per row

constexpr float LOG2E = 1.4426950408889634f;
constexpr float LN2   = 0.6931471805599453f;
constexpr float KAPPA = 0.999995f;
constexpr float ZCLMP = 16777216.0f;   // 2^24

__device__ __forceinline__ float fast_exp2(float x) { return __builtin_amdgcn_exp2f(x); }
__device__ __forceinline__ float fast_log2(float x) { return __builtin_amdgcn_logf(x); }
__device__ __forceinline__ float fast_rcp (float x) { return __builtin_amdgcn_rcpf(x); }

__global__ __launch_bounds__(T, 4)
void bp_decode(const float* __restrict__ llr,
               const float* __restrict__ w_iter,
               const float* __restrict__ llr_iter,
               const float* __restrict__ w_final,
               const float* __restrict__ llr_final,
               const int*  __restrict__ v_sum_idx,
               const int*  __restrict__ edge_var,
               const int*  __restrict__ final_idx,
               float* __restrict__ out)
{
    __shared__ v2f Ad[MCHK * STRIDE];   // 28672 B, d-messages (log2 domain), 2 rows packed

    const int  tid = threadIdx.x;
    const long b0  = (long)blockIdx.x * ROWS;

    // ---- init: c2v = 0 -> d = 0 ----
    #pragma unroll
    for (int k = 0; k < STRIDE; ++k)
        Ad[k * T + tid] = (v2f)(0.f);

    // ---- static per-thread graph data (my check = tid, my edges = 6*tid..6*tid+5) ----
    int nb[12];   // variable-side extrinsic neighbor edges of my 6 edges
    {
        const int4* p = (const int4*)(v_sum_idx + 12 * tid);  // 48B-aligned
        int4 q0 = p[0], q1 = p[1], q2 = p[2];
        nb[0]=q0.x; nb[1]=q0.y; nb[2]=q0.z; nb[3]=q0.w;
        nb[4]=q1.x; nb[5]=q1.y; nb[6]=q1.z; nb[7]=q1.w;
        nb[8]=q2.x; nb[9]=q2.y; nb[10]=q2.z; nb[11]=q2.w;
    }
    int goff[12];                     // padded LDS slot of each neighbor edge
    #pragma unroll
    for (int j = 0; j < 12; ++j)
        goff[j] = (nb[j] / 6) * STRIDE + (nb[j] % 6);

    int var[6];
    {
        const int2* p = (const int2*)(edge_var + 6 * tid);    // 24B-aligned
        int2 q0 = p[0], q1 = p[1], q2 = p[2];
        var[0]=q0.x; var[1]=q0.y; var[2]=q1.x; var[3]=q1.y; var[4]=q2.x; var[5]=q2.y;
    }

    // channel LLRs for my 6 variables, both batch rows (gathered once)
    v2f L[6];
    #pragma unroll
    for (int j = 0; j < 6; ++j) {
        L[j].x = llr[ b0      * NVAR + var[j]];
        L[j].y = llr[(b0 + 1) * NVAR + var[j]];
    }

    __syncthreads();

    const int own = STRIDE * tid;

    #pragma unroll 1
    for (int it = 0; it < NITER; ++it) {
        // per-iteration weights: my 6 edges x 2 = 12 consecutive floats (coalesced)
        const float* wit = w_iter + it * (EEDG * 2) + 12 * tid;
        float4 wa = ((const float4*)wit)[0];
        float4 wb = ((const float4*)wit)[1];
        float4 wc = ((const float4*)wit)[2];
        float w[12] = {wa.x,wa.y,wa.z,wa.w, wb.x,wb.y,wb.z,wb.w, wc.x,wc.y,wc.z,wc.w};

        // per-iteration llr multipliers (4KB L1-hot table)
        const float* lit = llr_iter + it * NVAR;
        v2f Lli[6];
        #pragma unroll
        for (int j = 0; j < 6; ++j) Lli[j] = L[j] * (lit[var[j]] * LOG2E);  // pk mul

        // gather extrinsic d-messages (12 x ds_read_b64)
        v2f g[12];
        #pragma unroll
        for (int j = 0; j < 12; ++j) g[j] = Ad[goff[j]];

        __syncthreads();   // all gathers landed before anyone overwrites in place

        // v2c in z-domain: z = exp2(sum w*d + llr*lw*log2e), clamped
        v2f zm[6], zp[6];
        #pragma unroll
        for (int j = 0; j < 6; ++j) {
            v2f a = w[2*j] * g[2*j] + w[2*j+1] * g[2*j+1] + Lli[j];   // 2x pk fma
            v2f z;
            z.x = fast_exp2(a.x);
            z.y = fast_exp2(a.y);
            z.x = fminf(z.x, ZCLMP);
            z.y = fminf(z.y, ZCLMP);
            zm[j] = z - 1.f;    // pk add
            zp[j] = z + 1.f;    // pk add
        }

        // all-but-one products of (z-1) and (z+1), in registers (pk muls)
        v2f A[6], B[6];
        {
            v2f P1=zm[0], P2=P1*zm[1], P3=P2*zm[2], P4=P3*zm[3], P5=P4*zm[4];
            v2f S4=zm[5], S3=S4*zm[4], S2=S3*zm[3], S1=S2*zm[2], S0=S1*zm[1];
            A[0]=S0; A[1]=P1*S1; A[2]=P2*S2; A[3]=P3*S3; A[4]=P4*S4; A[5]=P5;
        }
        {
            v2f P1=zp[0], P2=P1*zp[1], P3=P2*zp[2], P4=P3*zp[3], P5=P4*zp[4];
            v2f S4=zp[5], S3=S4*zp[4], S2=S3*zp[3], S1=S2*zp[2], S0=S1*zp[1];
            B[0]=S0; B[1]=P1*S1; B[2]=P2*S2; B[3]=P3*S3; B[4]=P4*S4; B[5]=P5;
        }

        // c2v: d = log2(B + k*A) - log2(B - k*A), written in place to my 6 slots
        #pragma unroll
        for (int j = 0; j < 6; ++j) {
            v2f num = KAPPA * A[j] + B[j];    // pk fma
            v2f den = B[j] - KAPPA * A[j];    // pk fma
            v2f d;
            d.x = fast_log2(num.x) - fast_log2(den.x);
            d.y = fast_log2(num.y) - fast_log2(den.y);
            Ad[own + j] = d;
        }

        __syncthreads();   // writes visible before next iteration's gathers
    }

    // ---- final marginalization: variable n = tid (exactly the 512 output vars) ----
    int f0 = final_idx[3*tid], f1 = final_idx[3*tid + 1], f2 = final_idx[3*tid + 2];
    v2f d0 = Ad[(f0 / 6) * STRIDE + (f0 % 6)];
    v2f d1 = Ad[(f1 / 6) * STRIDE + (f1 % 6)];
    v2f d2 = Ad[(f2 / 6) * STRIDE + (f2 % 6)];
    float wf0 = w_final[3*tid], wf1 = w_final[3*tid + 1], wf2 = w_final[3*tid + 2];
    float lf  = llr_final[tid];
    float l0  = llr[ b0      * NVAR + tid];
    float l1  = llr[(b0 + 1) * NVAR + tid];

    float finx = (d0.x*wf0 + d1.x*wf1 + d2.x*wf2) * LN2;   // c2v = ln2 * d
    float finy = (d0.y*wf0 + d1.y*wf1 + d2.y*wf2) * LN2;
    float vx = fmaf(l0, lf, finx);
    float vy = fmaf(l1, lf, finy);
    float ox = fast_rcp(1.f + fast_exp2(-vx * LOG2E));     // sigmoid
    float oy = fast_rcp(1.f + fast_exp2(-vy * LOG2E));

    out[ b0      * NOUT + tid] = ox;
    out[(b0 + 1) * NOUT + tid] = oy;
}

} // namespace

extern "C" void kernel_launch(void* const* d_in, const int* in_sizes, int n_in,
                              void* d_out, int out_size, void* d_ws, size_t ws_size,
                              hipStream_t stream)
{
    const float* llr       = (const float*)d_in[0];
    const float* w_iter    = (const float*)d_in[1];
    const float* llr_iter  = (const float*)d_in[2];
    const float* w_final   = (const float*)d_in[3];
    const float* llr_final = (const float*)d_in[4];
    const int*   v_sum_idx = (const int*)d_in[5];
    // d_in[6] = c_prod_idx: unused (check groups are consecutive by construction)
    const int*   edge_var  = (const int*)d_in[7];
    const int*   final_idx = (const int*)d_in[8];
    float* outp = (float*)d_out;

    dim3 grid(BATCH / ROWS), block(T);
    hipLaunchKernelGGL(bp_decode, grid, block, 0, stream,
                       llr, w_iter, llr_iter, w_final, llr_final,
                       v_sum_idx, edge_var, final_idx, outp);
}